// Round 13
// baseline (663.268 us; speedup 1.0000x reference)
//
#include <hip/hip_runtime.h>

#define N_PTS 400000
#define EPS 1e-5f
#define H_DELTA (11.0f / 255.0f)
#define H_INV_DELTA (255.0f / 11.0f)

typedef __attribute__((ext_vector_type(8))) short short8;
typedef __attribute__((ext_vector_type(4))) float f32x4;
typedef __attribute__((ext_vector_type(2))) float f32x2;
typedef __attribute__((ext_vector_type(2))) unsigned long long ull2;

// ws layout (bytes)
constexpr size_t H_OFF   = 0;                        // h  uint8 [N][64] (k-permuted) = 25,600,000 B
constexpr size_t H2_OFF  = 51200000;                 // h2 bf16 [N][64] = 51,200,000 B
constexpr size_t W1T_OFF = 102400000;                // w1t bf16 [64][128] = 16,384 B
constexpr size_t W2S_OFF = W1T_OFF + 16384;          // w2s bf16 [27][4096] (swizzled)
constexpr size_t W3T_OFF = W2S_OFF + 221184;         // w3t bf16 [128][64] = 16,384 B
constexpr size_t BNC_OFF = W3T_OFF + 16384;          // 512 f32

__device__ __forceinline__ short f2bf(float f) {
  unsigned u = __builtin_bit_cast(unsigned, f);
  u += 0x7FFFu + ((u >> 16) & 1u);   // RNE
  return (short)(u >> 16);
}

// HW packed f32->bf16 RNE (gfx950)
__device__ __forceinline__ unsigned cvtpk(float a, float b) {
  unsigned r;
  asm("v_cvt_pk_bf16_f32 %0, %1, %2" : "=v"(r) : "v"(a), "v"(b));
  return r;
}

// 8 uint8 -> 8 exact bf16 integers (ints 0..255 exact in bf16).
__device__ __forceinline__ short8 q2bf(unsigned long long v) {
  unsigned lo = (unsigned)v, hi = (unsigned)(v >> 32);
  union { unsigned u[4]; short8 s8; } r;
  r.u[0] = cvtpk((float)(lo & 0xff), (float)((lo >> 8) & 0xff));
  r.u[1] = cvtpk((float)((lo >> 16) & 0xff), (float)(lo >> 24));
  r.u[2] = cvtpk((float)(hi & 0xff), (float)((hi >> 8) & 0xff));
  r.u[3] = cvtpk((float)((hi >> 16) & 0xff), (float)(hi >> 24));
  return r.s8;
}

// ---------------- prep: weight transpose/convert + BN folding ----------------
__global__ __launch_bounds__(256) void prep_kernel(
    const float* __restrict__ w1, const float* __restrict__ w2,
    const float* __restrict__ w3,
    const float* __restrict__ g1, const float* __restrict__ b1,
    const float* __restrict__ m1, const float* __restrict__ v1,
    const float* __restrict__ g2, const float* __restrict__ b2,
    const float* __restrict__ m2, const float* __restrict__ v2,
    const float* __restrict__ g3, const float* __restrict__ b3,
    const float* __restrict__ m3, const float* __restrict__ v3,
    short* __restrict__ w1t, short* __restrict__ w2s,
    short* __restrict__ w3t, float* __restrict__ bnc) {
  int tid = blockIdx.x * 256 + threadIdx.x;
  int gs = gridDim.x * 256;
  for (int i = tid; i < 128 * 64; i += gs) {        // w1[k][n] -> w1t[n][k]
    int k = i >> 6, n = i & 63;
    w1t[n * 128 + k] = f2bf(w1[i]);
  }
  for (int i = tid; i < 27 * 64 * 64; i += gs) {    // w2[kk][k][n] -> swizzled w2s[kk][n][k]
    int kk = i >> 12, r = i & 4095, k = r >> 6, n = r & 63;
    int byte = (n * 64 + k) * 2;
    byte ^= (n & 7) << 4;                            // XOR swizzle (involution)
    w2s[kk * 4096 + (byte >> 1)] = f2bf(w2[i]);
  }
  for (int i = tid; i < 64 * 128; i += gs) {        // w3[k][n] -> w3t[n][k]
    int k = i >> 7, n = i & 127;
    w3t[n * 64 + k] = f2bf(w3[i]);
  }
  if (tid < 64) {
    float s = g1[tid] * rsqrtf(v1[tid] + EPS);
    bnc[tid] = s; bnc[64 + tid] = b1[tid] - m1[tid] * s;
  } else if (tid < 128) {
    int c = tid - 64;
    float s = g2[c] * rsqrtf(v2[c] + EPS);
    bnc[128 + c] = s; bnc[192 + c] = b2[c] - m2[c] * s;
  } else if (tid < 256) {
    int c = tid - 128;
    float s = g3[c] * rsqrtf(v3[c] + EPS);
    bnc[256 + c] = s; bnc[384 + c] = b3[c] - m3[c] * s;
  }
}

// ---------------- stage 1: h = quant_u8(relu(bn1(x @ w1))), k-permuted layout --
__global__ __launch_bounds__(256) void stage1_kernel(
    const float* __restrict__ x, const short* __restrict__ w1t,
    const float* __restrict__ bnc, unsigned char* __restrict__ h) {
  const int lane = threadIdx.x & 63;
  const int wid = threadIdx.x >> 6;
  const int lr = lane & 15, lk = lane >> 4;
  const long wbase = ((long)blockIdx.x * 4 + wid) * 64;
  if (wbase >= N_PTS) return;

  short8 bf[4][4];
#pragma unroll
  for (int nf = 0; nf < 4; ++nf)
#pragma unroll
    for (int ks = 0; ks < 4; ++ks)
      bf[nf][ks] = *(const short8*)(w1t + (nf * 16 + lr) * 128 + ks * 32 + lk * 8);

  float s[4], t[4];
#pragma unroll
  for (int nf = 0; nf < 4; ++nf) {
    int ch = nf * 16 + lr;
    s[nf] = bnc[ch]; t[nf] = bnc[64 + ch];
  }

#pragma unroll
  for (int mt = 0; mt < 4; ++mt) {
    f32x4 acc[4];
#pragma unroll
    for (int nf = 0; nf < 4; ++nf) acc[nf] = f32x4{0.f, 0.f, 0.f, 0.f};
    const float* xr = x + (wbase + mt * 16 + lr) * 128 + lk * 8;
#pragma unroll
    for (int ks = 0; ks < 4; ++ks) {
      f32x4 lo = *(const f32x4*)(xr + ks * 32);
      f32x4 hi = *(const f32x4*)(xr + ks * 32 + 4);
      union { unsigned u[4]; short8 s8; } av;
      av.u[0] = cvtpk(lo[0], lo[1]);
      av.u[1] = cvtpk(lo[2], lo[3]);
      av.u[2] = cvtpk(hi[0], hi[1]);
      av.u[3] = cvtpk(hi[2], hi[3]);
#pragma unroll
      for (int nf = 0; nf < 4; ++nf)
        acc[nf] = __builtin_amdgcn_mfma_f32_16x16x32_bf16(av.s8, bf[nf][ks], acc[nf], 0, 0, 0);
    }
    unsigned char* hr = h + (wbase + mt * 16) * 64;
#pragma unroll
    for (int nf = 0; nf < 4; ++nf) {
      // ch = nf*16+lr; pos = ((nf&1)*2 + (lr>>3))*16 + (nf>=2)*8 + (lr&7)
      int pos = (((nf & 1) * 2 + (lr >> 3)) << 4) + ((nf >> 1) << 3) + (lr & 7);
#pragma unroll
      for (int j = 0; j < 4; ++j) {
        int row = lk * 4 + j;
        float v = acc[nf][j] * s[nf] + t[nf];
        v = v > 0.f ? v : 0.f;
        unsigned qi = (unsigned)(v * H_INV_DELTA + 0.5f);
        if (qi > 255u) qi = 255u;
        hr[row * 64 + pos] = (unsigned char)qi;
      }
    }
  }
}

// ------- stage 2 (gather-GEMM, one 16B load per lane per row, 8 waves/EU):
// h2 = relu(bn2(DELTA * sum_k q[nb[k]]@w2[k]))
__global__ __launch_bounds__(256, 8) void stage2_kernel(
    const unsigned char* __restrict__ h, const int* __restrict__ nb,
    const short* __restrict__ w2s, const float* __restrict__ bnc,
    short* __restrict__ h2) {
  __shared__ __align__(16) short bbuf[2][4096];      // 16 KB double-buffered B
  const int tid = threadIdx.x;
  const int lane = tid & 63;
  const int wid = tid >> 6;
  const int lr = lane & 15, lk = lane >> 4;
  const long wbase = ((long)blockIdx.x * 4 + wid) * 32;
  const int chunk = tid ^ ((tid >> 3) & 3);          // bijective bank-spread permutation

  // swizzled LDS short-offsets for the 8 B-fragments
  int boff[4][2];
#pragma unroll
  for (int nf = 0; nf < 4; ++nf) {
    int row = nf * 16 + lr;
#pragma unroll
    for (int ks = 0; ks < 2; ++ks)
      boff[nf][ks] = ((row * 128 + ks * 64 + lk * 16) ^ ((row & 7) << 4)) >> 1;
  }

  f32x4 acc[2][4];
#pragma unroll
  for (int mt = 0; mt < 2; ++mt)
#pragma unroll
    for (int nf = 0; nf < 4; ++nf) acc[mt][nf] = f32x4{0.f, 0.f, 0.f, 0.f};

  const int* nb0 = nb + wbase + lr;            // + mt*16 + k*N_PTS

  int idxq[4][2];                               // ring, depth 4 (3 ahead)
  ull2 acur[2], anext[2];                       // 16B raw uint8 row chunk per mt

#pragma unroll
  for (int kk = 0; kk < 3; ++kk)
#pragma unroll
    for (int mt = 0; mt < 2; ++mt)
      idxq[kk][mt] = nb0[(long)kk * N_PTS + mt * 16];

#pragma unroll
  for (int mt = 0; mt < 2; ++mt)
    acur[mt] = *(const ull2*)(h + (long)idxq[0][mt] * 64 + lk * 16);

  {
    short8 b0a = *(const short8*)(w2s + chunk * 16);
    short8 b0b = *(const short8*)(w2s + chunk * 16 + 8);
    short8 b1a = *(const short8*)(w2s + 4096 + chunk * 16);
    short8 b1b = *(const short8*)(w2s + 4096 + chunk * 16 + 8);
    *(short8*)(&bbuf[0][chunk * 16]) = b0a;
    *(short8*)(&bbuf[0][chunk * 16 + 8]) = b0b;
    *(short8*)(&bbuf[1][chunk * 16]) = b1a;
    *(short8*)(&bbuf[1][chunk * 16 + 8]) = b1b;
  }
  asm volatile("s_waitcnt lgkmcnt(0)" ::: "memory");
  __builtin_amdgcn_s_barrier();

  // ---- main k-loop ----
#pragma unroll
  for (int k = 0; k < 27; ++k) {
    const int kp = k & 1;
    short8 bsa, bsb;
    if (k + 2 < 27) {               // B loads for k+2 (written to LDS after barrier)
      bsa = *(const short8*)(w2s + (k + 2) * 4096 + chunk * 16);
      bsb = *(const short8*)(w2s + (k + 2) * 4096 + chunk * 16 + 8);
    }
    if (k + 3 < 27) {               // idx loads for k+3 (depth-3 prefetch)
#pragma unroll
      for (int mt = 0; mt < 2; ++mt)
        idxq[(k + 3) & 3][mt] = nb0[(long)(k + 3) * N_PTS + mt * 16];
    }
    if (k + 1 < 27) {               // gathers for k+1: ONE dwordx4 per mt
#pragma unroll
      for (int mt = 0; mt < 2; ++mt)
        anext[mt] = *(const ull2*)(h + (long)idxq[(k + 1) & 3][mt] * 64 + lk * 16);
    }
    // unpack current-k A fragments (exact)
    short8 af[2][2];
#pragma unroll
    for (int mt = 0; mt < 2; ++mt) {
      af[mt][0] = q2bf(acur[mt][0]);
      af[mt][1] = q2bf(acur[mt][1]);
    }
    // MFMA on current k: B from LDS (swizzled)
#pragma unroll
    for (int nf = 0; nf < 4; ++nf) {
#pragma unroll
      for (int ks = 0; ks < 2; ++ks) {
        short8 bfr = *(const short8*)(&bbuf[kp][boff[nf][ks]]);
#pragma unroll
        for (int mt = 0; mt < 2; ++mt)
          acc[mt][nf] = __builtin_amdgcn_mfma_f32_16x16x32_bf16(af[mt][ks], bfr, acc[mt][nf], 0, 0, 0);
      }
    }
    asm volatile("s_waitcnt lgkmcnt(0)" ::: "memory");
    __builtin_amdgcn_s_barrier();
    if (k + 2 < 27) {               // write staged B into the buffer just freed
      *(short8*)(&bbuf[kp][chunk * 16]) = bsa;
      *(short8*)(&bbuf[kp][chunk * 16 + 8]) = bsb;
    }
    if (k + 1 < 27) {
#pragma unroll
      for (int mt = 0; mt < 2; ++mt)
        acur[mt] = anext[mt];
    }
  }

  // ---- bn2 + relu -> h2 (bf16); DELTA folded into the bn2 scale ----
  float s2[4], t2[4];
#pragma unroll
  for (int nf = 0; nf < 4; ++nf) {
    int ch = nf * 16 + lr;
    s2[nf] = bnc[128 + ch] * H_DELTA; t2[nf] = bnc[192 + ch];
  }

#pragma unroll
  for (int mt = 0; mt < 2; ++mt) {
    short* h2r = h2 + (wbase + mt * 16) * 64;
#pragma unroll
    for (int nf = 0; nf < 4; ++nf) {
      int ch = nf * 16 + lr;
#pragma unroll
      for (int j = 0; j < 4; ++j) {
        float v = acc[mt][nf][j] * s2[nf] + t2[nf];
        v = v > 0.f ? v : 0.f;
        h2r[(lk * 4 + j) * 64 + ch] = f2bf(v);
      }
    }
  }
}

// ---------------- stage 3: out = relu(bn3(h2 @ w3) + x) ----------------
__global__ __launch_bounds__(256) void stage3_kernel(
    const short* __restrict__ h2, const short* __restrict__ w3t,
    const float* __restrict__ bnc, const float* __restrict__ x,
    float* __restrict__ out) {
  __shared__ float tile3[4][16][130];   // f32, stride 130 (even, +2 pad)
  const int lane = threadIdx.x & 63;
  const int wid = threadIdx.x >> 6;
  const int lr = lane & 15, lk = lane >> 4;
  const long wbase = ((long)blockIdx.x * 4 + wid) * 64;
  if (wbase >= N_PTS) return;

  short8 b3[8][2];
#pragma unroll
  for (int nf = 0; nf < 8; ++nf)
#pragma unroll
    for (int ks = 0; ks < 2; ++ks)
      b3[nf][ks] = *(const short8*)(w3t + (nf * 16 + lr) * 64 + ks * 32 + lk * 8);

  float s3[8], t3[8];
#pragma unroll
  for (int nf = 0; nf < 8; ++nf) {
    int ch = nf * 16 + lr;
    s3[nf] = bnc[256 + ch]; t3[nf] = bnc[384 + ch];
  }

#pragma unroll
  for (int mt = 0; mt < 4; ++mt) {
    short8 a3[2];
#pragma unroll
    for (int ks = 0; ks < 2; ++ks)
      a3[ks] = *(const short8*)(h2 + (wbase + mt * 16 + lr) * 64 + ks * 32 + lk * 8);

    f32x4 acc3[8];
#pragma unroll
    for (int nf = 0; nf < 8; ++nf) acc3[nf] = f32x4{0.f, 0.f, 0.f, 0.f};
#pragma unroll
    for (int ks = 0; ks < 2; ++ks)
#pragma unroll
      for (int nf = 0; nf < 8; ++nf)
        acc3[nf] = __builtin_amdgcn_mfma_f32_16x16x32_bf16(a3[ks], b3[nf][ks], acc3[nf], 0, 0, 0);

    // bn3 -> LDS transpose tile (per-wave)
#pragma unroll
    for (int nf = 0; nf < 8; ++nf) {
      int ch = nf * 16 + lr;
#pragma unroll
      for (int j = 0; j < 4; ++j)
        tile3[wid][lk * 4 + j][ch] = acc3[nf][j] * s3[nf] + t3[nf];
    }
    asm volatile("s_waitcnt lgkmcnt(0)" ::: "memory");
    __builtin_amdgcn_sched_barrier(0);

    // per-row coalesced residual + relu + store
    const float* xr = x + (wbase + mt * 16) * 128 + 2 * lane;
    float* outr = out + (wbase + mt * 16) * 128 + 2 * lane;
#pragma unroll
    for (int r = 0; r < 16; ++r) {
      f32x2 tv = *(const f32x2*)&tile3[wid][r][2 * lane];
      f32x2 xv = *(const f32x2*)(xr + r * 128);
      float v0 = tv[0] + xv[0]; v0 = v0 > 0.f ? v0 : 0.f;
      float v1 = tv[1] + xv[1]; v1 = v1 > 0.f ? v1 : 0.f;
      *(f32x2*)(outr + r * 128) = f32x2{v0, v1};
    }
    __builtin_amdgcn_sched_barrier(0);
  }
}

extern "C" void kernel_launch(void* const* d_in, const int* in_sizes, int n_in,
                              void* d_out, int out_size, void* d_ws, size_t ws_size,
                              hipStream_t stream) {
  const float* x  = (const float*)d_in[0];
  const int*   nb = (const int*)d_in[1];
  const float* w1 = (const float*)d_in[2];
  const float* w2 = (const float*)d_in[3];
  const float* w3 = (const float*)d_in[4];
  const float* g1 = (const float*)d_in[5];
  const float* b1 = (const float*)d_in[6];
  const float* m1 = (const float*)d_in[7];
  const float* v1 = (const float*)d_in[8];
  const float* g2 = (const float*)d_in[9];
  const float* b2 = (const float*)d_in[10];
  const float* m2 = (const float*)d_in[11];
  const float* v2 = (const float*)d_in[12];
  const float* g3 = (const float*)d_in[13];
  const float* b3 = (const float*)d_in[14];
  const float* m3 = (const float*)d_in[15];
  const float* v3 = (const float*)d_in[16];

  char* ws = (char*)d_ws;
  unsigned char* hbuf = (unsigned char*)(ws + H_OFF);
  short* h2buf = (short*)(ws + H2_OFF);
  short* w1t   = (short*)(ws + W1T_OFF);
  short* w2s   = (short*)(ws + W2S_OFF);
  short* w3t   = (short*)(ws + W3T_OFF);
  float* bnc   = (float*)(ws + BNC_OFF);
  float* outp  = (float*)d_out;

  prep_kernel<<<128, 256, 0, stream>>>(w1, w2, w3,
                                       g1, b1, m1, v1,
                                       g2, b2, m2, v2,
                                       g3, b3, m3, v3,
                                       w1t, w2s, w3t, bnc);
  stage1_kernel<<<1563, 256, 0, stream>>>(x, w1t, bnc, hbuf);
  stage2_kernel<<<3125, 256, 0, stream>>>(hbuf, nb, w2s, bnc, h2buf);
  stage3_kernel<<<1563, 256, 0, stream>>>(h2buf, w3t, bnc, x, outp);
}

// Round 14
// 369.424 us; speedup vs baseline: 1.7954x; 1.7954x over previous
//
#include <hip/hip_runtime.h>

#define N_PTS 400000
#define EPS 1e-5f
#define H_DELTA (11.0f / 255.0f)
#define H_INV_DELTA (255.0f / 11.0f)

typedef __attribute__((ext_vector_type(8))) short short8;
typedef __attribute__((ext_vector_type(4))) float f32x4;
typedef __attribute__((ext_vector_type(2))) float f32x2;
typedef __attribute__((ext_vector_type(2))) unsigned long long ull2;

// ws layout (bytes)
constexpr size_t H_OFF   = 0;                        // h  uint8 [N][64] (k-permuted) = 25,600,000 B
constexpr size_t H2_OFF  = 51200000;                 // h2 bf16 [N][64] = 51,200,000 B
constexpr size_t W1T_OFF = 102400000;                // w1t bf16 [64][128] = 16,384 B
constexpr size_t W2S_OFF = W1T_OFF + 16384;          // w2s bf16 [27][4096] (swizzled)
constexpr size_t W3T_OFF = W2S_OFF + 221184;         // w3t bf16 [128][64] = 16,384 B
constexpr size_t BNC_OFF = W3T_OFF + 16384;          // 512 f32

__device__ __forceinline__ short f2bf(float f) {
  unsigned u = __builtin_bit_cast(unsigned, f);
  u += 0x7FFFu + ((u >> 16) & 1u);   // RNE
  return (short)(u >> 16);
}

// HW packed f32->bf16 RNE (gfx950)
__device__ __forceinline__ unsigned cvtpk(float a, float b) {
  unsigned r;
  asm("v_cvt_pk_bf16_f32 %0, %1, %2" : "=v"(r) : "v"(a), "v"(b));
  return r;
}

// 8 uint8 -> 8 exact bf16 integers (ints 0..255 exact in bf16).
__device__ __forceinline__ short8 q2bf(unsigned long long v) {
  unsigned lo = (unsigned)v, hi = (unsigned)(v >> 32);
  union { unsigned u[4]; short8 s8; } r;
  r.u[0] = cvtpk((float)(lo & 0xff), (float)((lo >> 8) & 0xff));
  r.u[1] = cvtpk((float)((lo >> 16) & 0xff), (float)(lo >> 24));
  r.u[2] = cvtpk((float)(hi & 0xff), (float)((hi >> 8) & 0xff));
  r.u[3] = cvtpk((float)((hi >> 16) & 0xff), (float)(hi >> 24));
  return r.s8;
}

// ---------------- prep: weight transpose/convert + BN folding ----------------
__global__ __launch_bounds__(256) void prep_kernel(
    const float* __restrict__ w1, const float* __restrict__ w2,
    const float* __restrict__ w3,
    const float* __restrict__ g1, const float* __restrict__ b1,
    const float* __restrict__ m1, const float* __restrict__ v1,
    const float* __restrict__ g2, const float* __restrict__ b2,
    const float* __restrict__ m2, const float* __restrict__ v2,
    const float* __restrict__ g3, const float* __restrict__ b3,
    const float* __restrict__ m3, const float* __restrict__ v3,
    short* __restrict__ w1t, short* __restrict__ w2s,
    short* __restrict__ w3t, float* __restrict__ bnc) {
  int tid = blockIdx.x * 256 + threadIdx.x;
  int gs = gridDim.x * 256;
  for (int i = tid; i < 128 * 64; i += gs) {        // w1[k][n] -> w1t[n][k]
    int k = i >> 6, n = i & 63;
    w1t[n * 128 + k] = f2bf(w1[i]);
  }
  for (int i = tid; i < 27 * 64 * 64; i += gs) {    // w2[kk][k][n] -> swizzled w2s[kk][n][k]
    int kk = i >> 12, r = i & 4095, k = r >> 6, n = r & 63;
    int byte = (n * 64 + k) * 2;
    byte ^= (n & 7) << 4;                            // XOR swizzle (involution)
    w2s[kk * 4096 + (byte >> 1)] = f2bf(w2[i]);
  }
  for (int i = tid; i < 64 * 128; i += gs) {        // w3[k][n] -> w3t[n][k]
    int k = i >> 7, n = i & 127;
    w3t[n * 64 + k] = f2bf(w3[i]);
  }
  if (tid < 64) {
    float s = g1[tid] * rsqrtf(v1[tid] + EPS);
    bnc[tid] = s; bnc[64 + tid] = b1[tid] - m1[tid] * s;
  } else if (tid < 128) {
    int c = tid - 64;
    float s = g2[c] * rsqrtf(v2[c] + EPS);
    bnc[128 + c] = s; bnc[192 + c] = b2[c] - m2[c] * s;
  } else if (tid < 256) {
    int c = tid - 128;
    float s = g3[c] * rsqrtf(v3[c] + EPS);
    bnc[256 + c] = s; bnc[384 + c] = b3[c] - m3[c] * s;
  }
}

// ---------------- stage 1: h = quant_u8(relu(bn1(x @ w1))), k-permuted layout --
__global__ __launch_bounds__(256) void stage1_kernel(
    const float* __restrict__ x, const short* __restrict__ w1t,
    const float* __restrict__ bnc, unsigned char* __restrict__ h) {
  const int lane = threadIdx.x & 63;
  const int wid = threadIdx.x >> 6;
  const int lr = lane & 15, lk = lane >> 4;
  const long wbase = ((long)blockIdx.x * 4 + wid) * 64;
  if (wbase >= N_PTS) return;

  short8 bf[4][4];
#pragma unroll
  for (int nf = 0; nf < 4; ++nf)
#pragma unroll
    for (int ks = 0; ks < 4; ++ks)
      bf[nf][ks] = *(const short8*)(w1t + (nf * 16 + lr) * 128 + ks * 32 + lk * 8);

  float s[4], t[4];
#pragma unroll
  for (int nf = 0; nf < 4; ++nf) {
    int ch = nf * 16 + lr;
    s[nf] = bnc[ch]; t[nf] = bnc[64 + ch];
  }

#pragma unroll
  for (int mt = 0; mt < 4; ++mt) {
    f32x4 acc[4];
#pragma unroll
    for (int nf = 0; nf < 4; ++nf) acc[nf] = f32x4{0.f, 0.f, 0.f, 0.f};
    const float* xr = x + (wbase + mt * 16 + lr) * 128 + lk * 8;
#pragma unroll
    for (int ks = 0; ks < 4; ++ks) {
      f32x4 lo = *(const f32x4*)(xr + ks * 32);
      f32x4 hi = *(const f32x4*)(xr + ks * 32 + 4);
      union { unsigned u[4]; short8 s8; } av;
      av.u[0] = cvtpk(lo[0], lo[1]);
      av.u[1] = cvtpk(lo[2], lo[3]);
      av.u[2] = cvtpk(hi[0], hi[1]);
      av.u[3] = cvtpk(hi[2], hi[3]);
#pragma unroll
      for (int nf = 0; nf < 4; ++nf)
        acc[nf] = __builtin_amdgcn_mfma_f32_16x16x32_bf16(av.s8, bf[nf][ks], acc[nf], 0, 0, 0);
    }
    unsigned char* hr = h + (wbase + mt * 16) * 64;
#pragma unroll
    for (int nf = 0; nf < 4; ++nf) {
      // ch = nf*16+lr; pos = ((nf&1)*2 + (lr>>3))*16 + (nf>=2)*8 + (lr&7)
      int pos = (((nf & 1) * 2 + (lr >> 3)) << 4) + ((nf >> 1) << 3) + (lr & 7);
#pragma unroll
      for (int j = 0; j < 4; ++j) {
        int row = lk * 4 + j;
        float v = acc[nf][j] * s[nf] + t[nf];
        v = v > 0.f ? v : 0.f;
        unsigned qi = (unsigned)(v * H_INV_DELTA + 0.5f);
        if (qi > 255u) qi = 255u;
        hr[row * 64 + pos] = (unsigned char)qi;
      }
    }
  }
}

// ------- stage 2 (gather-GEMM, one 16B load per lane per row, 6 waves/EU):
// h2 = relu(bn2(DELTA * sum_k q[nb[k]]@w2[k]))
// (256,6): VGPR budget ~85 > 60 used -> no spill; occupancy cap 16 -> 24 waves/CU.
__global__ __launch_bounds__(256, 6) void stage2_kernel(
    const unsigned char* __restrict__ h, const int* __restrict__ nb,
    const short* __restrict__ w2s, const float* __restrict__ bnc,
    short* __restrict__ h2) {
  __shared__ __align__(16) short bbuf[2][4096];      // 16 KB double-buffered B
  const int tid = threadIdx.x;
  const int lane = tid & 63;
  const int wid = tid >> 6;
  const int lr = lane & 15, lk = lane >> 4;
  const long wbase = ((long)blockIdx.x * 4 + wid) * 32;
  const int chunk = tid ^ ((tid >> 3) & 3);          // bijective bank-spread permutation

  // swizzled LDS short-offsets for the 8 B-fragments
  int boff[4][2];
#pragma unroll
  for (int nf = 0; nf < 4; ++nf) {
    int row = nf * 16 + lr;
#pragma unroll
    for (int ks = 0; ks < 2; ++ks)
      boff[nf][ks] = ((row * 128 + ks * 64 + lk * 16) ^ ((row & 7) << 4)) >> 1;
  }

  f32x4 acc[2][4];
#pragma unroll
  for (int mt = 0; mt < 2; ++mt)
#pragma unroll
    for (int nf = 0; nf < 4; ++nf) acc[mt][nf] = f32x4{0.f, 0.f, 0.f, 0.f};

  const int* nb0 = nb + wbase + lr;            // + mt*16 + k*N_PTS

  int idxq[4][2];                               // ring, depth 4 (3 ahead)
  ull2 acur[2], anext[2];                       // 16B raw uint8 row chunk per mt

#pragma unroll
  for (int kk = 0; kk < 3; ++kk)
#pragma unroll
    for (int mt = 0; mt < 2; ++mt)
      idxq[kk][mt] = nb0[(long)kk * N_PTS + mt * 16];

#pragma unroll
  for (int mt = 0; mt < 2; ++mt)
    acur[mt] = *(const ull2*)(h + (long)idxq[0][mt] * 64 + lk * 16);

  {
    short8 b0a = *(const short8*)(w2s + chunk * 16);
    short8 b0b = *(const short8*)(w2s + chunk * 16 + 8);
    short8 b1a = *(const short8*)(w2s + 4096 + chunk * 16);
    short8 b1b = *(const short8*)(w2s + 4096 + chunk * 16 + 8);
    *(short8*)(&bbuf[0][chunk * 16]) = b0a;
    *(short8*)(&bbuf[0][chunk * 16 + 8]) = b0b;
    *(short8*)(&bbuf[1][chunk * 16]) = b1a;
    *(short8*)(&bbuf[1][chunk * 16 + 8]) = b1b;
  }
  asm volatile("s_waitcnt lgkmcnt(0)" ::: "memory");
  __builtin_amdgcn_s_barrier();

  // ---- main k-loop ----
#pragma unroll
  for (int k = 0; k < 27; ++k) {
    const int kp = k & 1;
    short8 bsa, bsb;
    if (k + 2 < 27) {               // B loads for k+2 (written to LDS after barrier)
      bsa = *(const short8*)(w2s + (k + 2) * 4096 + chunk * 16);
      bsb = *(const short8*)(w2s + (k + 2) * 4096 + chunk * 16 + 8);
    }
    if (k + 3 < 27) {               // idx loads for k+3 (depth-3 prefetch)
#pragma unroll
      for (int mt = 0; mt < 2; ++mt)
        idxq[(k + 3) & 3][mt] = nb0[(long)(k + 3) * N_PTS + mt * 16];
    }
    if (k + 1 < 27) {               // gathers for k+1: ONE dwordx4 per mt
#pragma unroll
      for (int mt = 0; mt < 2; ++mt)
        anext[mt] = *(const ull2*)(h + (long)idxq[(k + 1) & 3][mt] * 64 + lk * 16);
    }
    // unpack current-k A fragments (exact)
    short8 af[2][2];
#pragma unroll
    for (int mt = 0; mt < 2; ++mt) {
      af[mt][0] = q2bf(acur[mt][0]);
      af[mt][1] = q2bf(acur[mt][1]);
    }
    // MFMA on current k: B from LDS (swizzled)
#pragma unroll
    for (int nf = 0; nf < 4; ++nf) {
#pragma unroll
      for (int ks = 0; ks < 2; ++ks) {
        short8 bfr = *(const short8*)(&bbuf[kp][boff[nf][ks]]);
#pragma unroll
        for (int mt = 0; mt < 2; ++mt)
          acc[mt][nf] = __builtin_amdgcn_mfma_f32_16x16x32_bf16(af[mt][ks], bfr, acc[mt][nf], 0, 0, 0);
      }
    }
    asm volatile("s_waitcnt lgkmcnt(0)" ::: "memory");
    __builtin_amdgcn_s_barrier();
    if (k + 2 < 27) {               // write staged B into the buffer just freed
      *(short8*)(&bbuf[kp][chunk * 16]) = bsa;
      *(short8*)(&bbuf[kp][chunk * 16 + 8]) = bsb;
    }
    if (k + 1 < 27) {
#pragma unroll
      for (int mt = 0; mt < 2; ++mt)
        acur[mt] = anext[mt];
    }
  }

  // ---- bn2 + relu -> h2 (bf16); DELTA folded into the bn2 scale ----
  float s2[4], t2[4];
#pragma unroll
  for (int nf = 0; nf < 4; ++nf) {
    int ch = nf * 16 + lr;
    s2[nf] = bnc[128 + ch] * H_DELTA; t2[nf] = bnc[192 + ch];
  }

#pragma unroll
  for (int mt = 0; mt < 2; ++mt) {
    short* h2r = h2 + (wbase + mt * 16) * 64;
#pragma unroll
    for (int nf = 0; nf < 4; ++nf) {
      int ch = nf * 16 + lr;
#pragma unroll
      for (int j = 0; j < 4; ++j) {
        float v = acc[mt][nf][j] * s2[nf] + t2[nf];
        v = v > 0.f ? v : 0.f;
        h2r[(lk * 4 + j) * 64 + ch] = f2bf(v);
      }
    }
  }
}

// ---------------- stage 3: out = relu(bn3(h2 @ w3) + x) ----------------
__global__ __launch_bounds__(256) void stage3_kernel(
    const short* __restrict__ h2, const short* __restrict__ w3t,
    const float* __restrict__ bnc, const float* __restrict__ x,
    float* __restrict__ out) {
  __shared__ float tile3[4][16][130];   // f32, stride 130 (even, +2 pad)
  const int lane = threadIdx.x & 63;
  const int wid = threadIdx.x >> 6;
  const int lr = lane & 15, lk = lane >> 4;
  const long wbase = ((long)blockIdx.x * 4 + wid) * 64;
  if (wbase >= N_PTS) return;

  short8 b3[8][2];
#pragma unroll
  for (int nf = 0; nf < 8; ++nf)
#pragma unroll
    for (int ks = 0; ks < 2; ++ks)
      b3[nf][ks] = *(const short8*)(w3t + (nf * 16 + lr) * 64 + ks * 32 + lk * 8);

  float s3[8], t3[8];
#pragma unroll
  for (int nf = 0; nf < 8; ++nf) {
    int ch = nf * 16 + lr;
    s3[nf] = bnc[256 + ch]; t3[nf] = bnc[384 + ch];
  }

#pragma unroll
  for (int mt = 0; mt < 4; ++mt) {
    short8 a3[2];
#pragma unroll
    for (int ks = 0; ks < 2; ++ks)
      a3[ks] = *(const short8*)(h2 + (wbase + mt * 16 + lr) * 64 + ks * 32 + lk * 8);

    f32x4 acc3[8];
#pragma unroll
    for (int nf = 0; nf < 8; ++nf) acc3[nf] = f32x4{0.f, 0.f, 0.f, 0.f};
#pragma unroll
    for (int ks = 0; ks < 2; ++ks)
#pragma unroll
      for (int nf = 0; nf < 8; ++nf)
        acc3[nf] = __builtin_amdgcn_mfma_f32_16x16x32_bf16(a3[ks], b3[nf][ks], acc3[nf], 0, 0, 0);

    // bn3 -> LDS transpose tile (per-wave)
#pragma unroll
    for (int nf = 0; nf < 8; ++nf) {
      int ch = nf * 16 + lr;
#pragma unroll
      for (int j = 0; j < 4; ++j)
        tile3[wid][lk * 4 + j][ch] = acc3[nf][j] * s3[nf] + t3[nf];
    }
    asm volatile("s_waitcnt lgkmcnt(0)" ::: "memory");
    __builtin_amdgcn_sched_barrier(0);

    // per-row coalesced residual + relu + store
    const float* xr = x + (wbase + mt * 16) * 128 + 2 * lane;
    float* outr = out + (wbase + mt * 16) * 128 + 2 * lane;
#pragma unroll
    for (int r = 0; r < 16; ++r) {
      f32x2 tv = *(const f32x2*)&tile3[wid][r][2 * lane];
      f32x2 xv = *(const f32x2*)(xr + r * 128);
      float v0 = tv[0] + xv[0]; v0 = v0 > 0.f ? v0 : 0.f;
      float v1 = tv[1] + xv[1]; v1 = v1 > 0.f ? v1 : 0.f;
      *(f32x2*)(outr + r * 128) = f32x2{v0, v1};
    }
    __builtin_amdgcn_sched_barrier(0);
  }
}

extern "C" void kernel_launch(void* const* d_in, const int* in_sizes, int n_in,
                              void* d_out, int out_size, void* d_ws, size_t ws_size,
                              hipStream_t stream) {
  const float* x  = (const float*)d_in[0];
  const int*   nb = (const int*)d_in[1];
  const float* w1 = (const float*)d_in[2];
  const float* w2 = (const float*)d_in[3];
  const float* w3 = (const float*)d_in[4];
  const float* g1 = (const float*)d_in[5];
  const float* b1 = (const float*)d_in[6];
  const float* m1 = (const float*)d_in[7];
  const float* v1 = (const float*)d_in[8];
  const float* g2 = (const float*)d_in[9];
  const float* b2 = (const float*)d_in[10];
  const float* m2 = (const float*)d_in[11];
  const float* v2 = (const float*)d_in[12];
  const float* g3 = (const float*)d_in[13];
  const float* b3 = (const float*)d_in[14];
  const float* m3 = (const float*)d_in[15];
  const float* v3 = (const float*)d_in[16];

  char* ws = (char*)d_ws;
  unsigned char* hbuf = (unsigned char*)(ws + H_OFF);
  short* h2buf = (short*)(ws + H2_OFF);
  short* w1t   = (short*)(ws + W1T_OFF);
  short* w2s   = (short*)(ws + W2S_OFF);
  short* w3t   = (short*)(ws + W3T_OFF);
  float* bnc   = (float*)(ws + BNC_OFF);
  float* outp  = (float*)d_out;

  prep_kernel<<<128, 256, 0, stream>>>(w1, w2, w3,
                                       g1, b1, m1, v1,
                                       g2, b2, m2, v2,
                                       g3, b3, m3, v3,
                                       w1t, w2s, w3t, bnc);
  stage1_kernel<<<1563, 256, 0, stream>>>(x, w1t, bnc, hbuf);
  stage2_kernel<<<3125, 256, 0, stream>>>(hbuf, nb, w2s, bnc, h2buf);
  stage3_kernel<<<1563, 256, 0, stream>>>(h2buf, w3t, bnc, x, outp);
}

// Round 15
// 328.370 us; speedup vs baseline: 2.0199x; 1.1250x over previous
//
#include <hip/hip_runtime.h>

#define N_PTS 400000
#define EPS 1e-5f
#define H_DELTA (11.0f / 255.0f)
#define H_INV_DELTA (255.0f / 11.0f)

typedef __attribute__((ext_vector_type(8))) short short8;
typedef __attribute__((ext_vector_type(4))) float f32x4;
typedef __attribute__((ext_vector_type(2))) float f32x2;
typedef __attribute__((ext_vector_type(2))) unsigned long long ull2;

// ws layout (bytes)
constexpr size_t H_OFF   = 0;                        // h  uint8 [N][64] (k-permuted) = 25,600,000 B
constexpr size_t H2_OFF  = 51200000;                 // h2 bf16 [N][64] = 51,200,000 B
constexpr size_t W1T_OFF = 102400000;                // w1t bf16 [64][128] = 16,384 B
constexpr size_t W2S_OFF = W1T_OFF + 16384;          // w2s bf16 [27][4096] (swizzled)
constexpr size_t W3T_OFF = W2S_OFF + 221184;         // w3t bf16 [128][64] = 16,384 B
constexpr size_t BNC_OFF = W3T_OFF + 16384;          // 512 f32

__device__ __forceinline__ short f2bf(float f) {
  unsigned u = __builtin_bit_cast(unsigned, f);
  u += 0x7FFFu + ((u >> 16) & 1u);   // RNE
  return (short)(u >> 16);
}

// HW packed f32->bf16 RNE (gfx950)
__device__ __forceinline__ unsigned cvtpk(float a, float b) {
  unsigned r;
  asm("v_cvt_pk_bf16_f32 %0, %1, %2" : "=v"(r) : "v"(a), "v"(b));
  return r;
}

// 8 uint8 -> 8 exact bf16 integers (ints 0..255 exact in bf16).
__device__ __forceinline__ short8 q2bf(unsigned long long v) {
  unsigned lo = (unsigned)v, hi = (unsigned)(v >> 32);
  union { unsigned u[4]; short8 s8; } r;
  r.u[0] = cvtpk((float)(lo & 0xff), (float)((lo >> 8) & 0xff));
  r.u[1] = cvtpk((float)((lo >> 16) & 0xff), (float)(lo >> 24));
  r.u[2] = cvtpk((float)(hi & 0xff), (float)((hi >> 8) & 0xff));
  r.u[3] = cvtpk((float)((hi >> 16) & 0xff), (float)(hi >> 24));
  return r.s8;
}

// ---------------- prep: weight transpose/convert + BN folding ----------------
__global__ __launch_bounds__(256) void prep_kernel(
    const float* __restrict__ w1, const float* __restrict__ w2,
    const float* __restrict__ w3,
    const float* __restrict__ g1, const float* __restrict__ b1,
    const float* __restrict__ m1, const float* __restrict__ v1,
    const float* __restrict__ g2, const float* __restrict__ b2,
    const float* __restrict__ m2, const float* __restrict__ v2,
    const float* __restrict__ g3, const float* __restrict__ b3,
    const float* __restrict__ m3, const float* __restrict__ v3,
    short* __restrict__ w1t, short* __restrict__ w2s,
    short* __restrict__ w3t, float* __restrict__ bnc) {
  int tid = blockIdx.x * 256 + threadIdx.x;
  int gs = gridDim.x * 256;
  for (int i = tid; i < 128 * 64; i += gs) {        // w1[k][n] -> w1t[n][k]
    int k = i >> 6, n = i & 63;
    w1t[n * 128 + k] = f2bf(w1[i]);
  }
  for (int i = tid; i < 27 * 64 * 64; i += gs) {    // w2[kk][k][n] -> swizzled w2s[kk][n][k]
    int kk = i >> 12, r = i & 4095, k = r >> 6, n = r & 63;
    int byte = (n * 64 + k) * 2;
    byte ^= (n & 7) << 4;                            // XOR swizzle (involution)
    w2s[kk * 4096 + (byte >> 1)] = f2bf(w2[i]);
  }
  for (int i = tid; i < 64 * 128; i += gs) {        // w3[k][n] -> w3t[n][k]
    int k = i >> 7, n = i & 127;
    w3t[n * 64 + k] = f2bf(w3[i]);
  }
  if (tid < 64) {
    float s = g1[tid] * rsqrtf(v1[tid] + EPS);
    bnc[tid] = s; bnc[64 + tid] = b1[tid] - m1[tid] * s;
  } else if (tid < 128) {
    int c = tid - 64;
    float s = g2[c] * rsqrtf(v2[c] + EPS);
    bnc[128 + c] = s; bnc[192 + c] = b2[c] - m2[c] * s;
  } else if (tid < 256) {
    int c = tid - 128;
    float s = g3[c] * rsqrtf(v3[c] + EPS);
    bnc[256 + c] = s; bnc[384 + c] = b3[c] - m3[c] * s;
  }
}

// ---------------- stage 1: h = quant_u8(relu(bn1(x @ w1))), k-permuted layout --
// Epilogue via per-wave LDS tile -> coalesced 16B stores (16x fewer store reqs).
__global__ __launch_bounds__(256) void stage1_kernel(
    const float* __restrict__ x, const short* __restrict__ w1t,
    const float* __restrict__ bnc, unsigned char* __restrict__ h) {
  __shared__ __align__(16) unsigned char t1[4][16][80];   // u8, 16B-aligned rows
  const int lane = threadIdx.x & 63;
  const int wid = threadIdx.x >> 6;
  const int lr = lane & 15, lk = lane >> 4;
  const long wbase = ((long)blockIdx.x * 4 + wid) * 64;
  if (wbase >= N_PTS) return;

  short8 bf[4][4];
#pragma unroll
  for (int nf = 0; nf < 4; ++nf)
#pragma unroll
    for (int ks = 0; ks < 4; ++ks)
      bf[nf][ks] = *(const short8*)(w1t + (nf * 16 + lr) * 128 + ks * 32 + lk * 8);

  float s[4], t[4];
#pragma unroll
  for (int nf = 0; nf < 4; ++nf) {
    int ch = nf * 16 + lr;
    s[nf] = bnc[ch]; t[nf] = bnc[64 + ch];
  }

#pragma unroll
  for (int mt = 0; mt < 4; ++mt) {
    f32x4 acc[4];
#pragma unroll
    for (int nf = 0; nf < 4; ++nf) acc[nf] = f32x4{0.f, 0.f, 0.f, 0.f};
    const float* xr = x + (wbase + mt * 16 + lr) * 128 + lk * 8;
#pragma unroll
    for (int ks = 0; ks < 4; ++ks) {
      f32x4 lo = *(const f32x4*)(xr + ks * 32);
      f32x4 hi = *(const f32x4*)(xr + ks * 32 + 4);
      union { unsigned u[4]; short8 s8; } av;
      av.u[0] = cvtpk(lo[0], lo[1]);
      av.u[1] = cvtpk(lo[2], lo[3]);
      av.u[2] = cvtpk(hi[0], hi[1]);
      av.u[3] = cvtpk(hi[2], hi[3]);
#pragma unroll
      for (int nf = 0; nf < 4; ++nf)
        acc[nf] = __builtin_amdgcn_mfma_f32_16x16x32_bf16(av.s8, bf[nf][ks], acc[nf], 0, 0, 0);
    }
    // quantize -> per-wave LDS tile (k-permuted positions)
#pragma unroll
    for (int nf = 0; nf < 4; ++nf) {
      // ch = nf*16+lr; pos = ((nf&1)*2 + (lr>>3))*16 + (nf>=2)*8 + (lr&7)
      int pos = (((nf & 1) * 2 + (lr >> 3)) << 4) + ((nf >> 1) << 3) + (lr & 7);
#pragma unroll
      for (int j = 0; j < 4; ++j) {
        float v = acc[nf][j] * s[nf] + t[nf];
        v = v > 0.f ? v : 0.f;
        unsigned qi = (unsigned)(v * H_INV_DELTA + 0.5f);
        if (qi > 255u) qi = 255u;
        t1[wid][lk * 4 + j][pos] = (unsigned char)qi;
      }
    }
    asm volatile("s_waitcnt lgkmcnt(0)" ::: "memory");
    __builtin_amdgcn_sched_barrier(0);
    // coalesced store: lane -> (row = lane>>2, chunk = lane&3), 1KB contiguous per wave
    {
      int row = lane >> 2, c = lane & 3;
      ull2 v = *(const ull2*)&t1[wid][row][c * 16];
      *(ull2*)(h + (wbase + mt * 16 + row) * 64 + c * 16) = v;
    }
    __builtin_amdgcn_sched_barrier(0);
  }
}

// ------- stage 2 (gather-GEMM, one 16B load per lane per row; R12 config):
// h2 = relu(bn2(DELTA * sum_k q[nb[k]]@w2[k]))
__global__ __launch_bounds__(256, 4) void stage2_kernel(
    const unsigned char* __restrict__ h, const int* __restrict__ nb,
    const short* __restrict__ w2s, const float* __restrict__ bnc,
    short* __restrict__ h2) {
  __shared__ __align__(16) short bbuf[2][4096];      // 16 KB double-buffered B
  const int tid = threadIdx.x;
  const int lane = tid & 63;
  const int wid = tid >> 6;
  const int lr = lane & 15, lk = lane >> 4;
  const long wbase = ((long)blockIdx.x * 4 + wid) * 32;
  const int chunk = tid ^ ((tid >> 3) & 3);          // bijective bank-spread permutation

  // swizzled LDS short-offsets for the 8 B-fragments
  int boff[4][2];
#pragma unroll
  for (int nf = 0; nf < 4; ++nf) {
    int row = nf * 16 + lr;
#pragma unroll
    for (int ks = 0; ks < 2; ++ks)
      boff[nf][ks] = ((row * 128 + ks * 64 + lk * 16) ^ ((row & 7) << 4)) >> 1;
  }

  f32x4 acc[2][4];
#pragma unroll
  for (int mt = 0; mt < 2; ++mt)
#pragma unroll
    for (int nf = 0; nf < 4; ++nf) acc[mt][nf] = f32x4{0.f, 0.f, 0.f, 0.f};

  const int* nb0 = nb + wbase + lr;            // + mt*16 + k*N_PTS

  int idxq[4][2];                               // ring, depth 4 (3 ahead)
  ull2 acur[2], anext[2];                       // 16B raw uint8 row chunk per mt

#pragma unroll
  for (int kk = 0; kk < 3; ++kk)
#pragma unroll
    for (int mt = 0; mt < 2; ++mt)
      idxq[kk][mt] = nb0[(long)kk * N_PTS + mt * 16];

#pragma unroll
  for (int mt = 0; mt < 2; ++mt)
    acur[mt] = *(const ull2*)(h + (long)idxq[0][mt] * 64 + lk * 16);

  {
    short8 b0a = *(const short8*)(w2s + chunk * 16);
    short8 b0b = *(const short8*)(w2s + chunk * 16 + 8);
    short8 b1a = *(const short8*)(w2s + 4096 + chunk * 16);
    short8 b1b = *(const short8*)(w2s + 4096 + chunk * 16 + 8);
    *(short8*)(&bbuf[0][chunk * 16]) = b0a;
    *(short8*)(&bbuf[0][chunk * 16 + 8]) = b0b;
    *(short8*)(&bbuf[1][chunk * 16]) = b1a;
    *(short8*)(&bbuf[1][chunk * 16 + 8]) = b1b;
  }
  asm volatile("s_waitcnt lgkmcnt(0)" ::: "memory");
  __builtin_amdgcn_s_barrier();

  // ---- main k-loop ----
#pragma unroll
  for (int k = 0; k < 27; ++k) {
    const int kp = k & 1;
    short8 bsa, bsb;
    if (k + 2 < 27) {               // B loads for k+2 (written to LDS after barrier)
      bsa = *(const short8*)(w2s + (k + 2) * 4096 + chunk * 16);
      bsb = *(const short8*)(w2s + (k + 2) * 4096 + chunk * 16 + 8);
    }
    if (k + 3 < 27) {               // idx loads for k+3 (depth-3 prefetch)
#pragma unroll
      for (int mt = 0; mt < 2; ++mt)
        idxq[(k + 3) & 3][mt] = nb0[(long)(k + 3) * N_PTS + mt * 16];
    }
    if (k + 1 < 27) {               // gathers for k+1: ONE dwordx4 per mt
#pragma unroll
      for (int mt = 0; mt < 2; ++mt)
        anext[mt] = *(const ull2*)(h + (long)idxq[(k + 1) & 3][mt] * 64 + lk * 16);
    }
    // unpack current-k A fragments (exact)
    short8 af[2][2];
#pragma unroll
    for (int mt = 0; mt < 2; ++mt) {
      af[mt][0] = q2bf(acur[mt][0]);
      af[mt][1] = q2bf(acur[mt][1]);
    }
    // MFMA on current k: B from LDS (swizzled)
#pragma unroll
    for (int nf = 0; nf < 4; ++nf) {
#pragma unroll
      for (int ks = 0; ks < 2; ++ks) {
        short8 bfr = *(const short8*)(&bbuf[kp][boff[nf][ks]]);
#pragma unroll
        for (int mt = 0; mt < 2; ++mt)
          acc[mt][nf] = __builtin_amdgcn_mfma_f32_16x16x32_bf16(af[mt][ks], bfr, acc[mt][nf], 0, 0, 0);
      }
    }
    asm volatile("s_waitcnt lgkmcnt(0)" ::: "memory");
    __builtin_amdgcn_s_barrier();
    if (k + 2 < 27) {               // write staged B into the buffer just freed
      *(short8*)(&bbuf[kp][chunk * 16]) = bsa;
      *(short8*)(&bbuf[kp][chunk * 16 + 8]) = bsb;
    }
    if (k + 1 < 27) {
#pragma unroll
      for (int mt = 0; mt < 2; ++mt)
        acur[mt] = anext[mt];
    }
  }

  // ---- bn2 + relu -> h2 (bf16); DELTA folded into the bn2 scale ----
  float s2[4], t2[4];
#pragma unroll
  for (int nf = 0; nf < 4; ++nf) {
    int ch = nf * 16 + lr;
    s2[nf] = bnc[128 + ch] * H_DELTA; t2[nf] = bnc[192 + ch];
  }

#pragma unroll
  for (int mt = 0; mt < 2; ++mt) {
    short* h2r = h2 + (wbase + mt * 16) * 64;
#pragma unroll
    for (int nf = 0; nf < 4; ++nf) {
      int ch = nf * 16 + lr;
#pragma unroll
      for (int j = 0; j < 4; ++j) {
        float v = acc[mt][nf][j] * s2[nf] + t2[nf];
        v = v > 0.f ? v : 0.f;
        h2r[(lk * 4 + j) * 64 + ch] = f2bf(v);
      }
    }
  }
}

// ---------------- stage 3: out = relu(bn3(h2 @ w3) + x) ----------------
__global__ __launch_bounds__(256) void stage3_kernel(
    const short* __restrict__ h2, const short* __restrict__ w3t,
    const float* __restrict__ bnc, const float* __restrict__ x,
    float* __restrict__ out) {
  __shared__ float tile3[4][16][130];   // f32, stride 130 (even, +2 pad)
  const int lane = threadIdx.x & 63;
  const int wid = threadIdx.x >> 6;
  const int lr = lane & 15, lk = lane >> 4;
  const long wbase = ((long)blockIdx.x * 4 + wid) * 64;
  if (wbase >= N_PTS) return;

  short8 b3[8][2];
#pragma unroll
  for (int nf = 0; nf < 8; ++nf)
#pragma unroll
    for (int ks = 0; ks < 2; ++ks)
      b3[nf][ks] = *(const short8*)(w3t + (nf * 16 + lr) * 64 + ks * 32 + lk * 8);

  float s3[8], t3[8];
#pragma unroll
  for (int nf = 0; nf < 8; ++nf) {
    int ch = nf * 16 + lr;
    s3[nf] = bnc[256 + ch]; t3[nf] = bnc[384 + ch];
  }

#pragma unroll
  for (int mt = 0; mt < 4; ++mt) {
    short8 a3[2];
#pragma unroll
    for (int ks = 0; ks < 2; ++ks)
      a3[ks] = *(const short8*)(h2 + (wbase + mt * 16 + lr) * 64 + ks * 32 + lk * 8);

    f32x4 acc3[8];
#pragma unroll
    for (int nf = 0; nf < 8; ++nf) acc3[nf] = f32x4{0.f, 0.f, 0.f, 0.f};
#pragma unroll
    for (int ks = 0; ks < 2; ++ks)
#pragma unroll
      for (int nf = 0; nf < 8; ++nf)
        acc3[nf] = __builtin_amdgcn_mfma_f32_16x16x32_bf16(a3[ks], b3[nf][ks], acc3[nf], 0, 0, 0);

    // bn3 -> LDS transpose tile (per-wave)
#pragma unroll
    for (int nf = 0; nf < 8; ++nf) {
      int ch = nf * 16 + lr;
#pragma unroll
      for (int j = 0; j < 4; ++j)
        tile3[wid][lk * 4 + j][ch] = acc3[nf][j] * s3[nf] + t3[nf];
    }
    asm volatile("s_waitcnt lgkmcnt(0)" ::: "memory");
    __builtin_amdgcn_sched_barrier(0);

    // per-row coalesced residual + relu + store
    const float* xr = x + (wbase + mt * 16) * 128 + 2 * lane;
    float* outr = out + (wbase + mt * 16) * 128 + 2 * lane;
#pragma unroll
    for (int r = 0; r < 16; ++r) {
      f32x2 tv = *(const f32x2*)&tile3[wid][r][2 * lane];
      f32x2 xv = *(const f32x2*)(xr + r * 128);
      float v0 = tv[0] + xv[0]; v0 = v0 > 0.f ? v0 : 0.f;
      float v1 = tv[1] + xv[1]; v1 = v1 > 0.f ? v1 : 0.f;
      *(f32x2*)(outr + r * 128) = f32x2{v0, v1};
    }
    __builtin_amdgcn_sched_barrier(0);
  }
}

extern "C" void kernel_launch(void* const* d_in, const int* in_sizes, int n_in,
                              void* d_out, int out_size, void* d_ws, size_t ws_size,
                              hipStream_t stream) {
  const float* x  = (const float*)d_in[0];
  const int*   nb = (const int*)d_in[1];
  const float* w1 = (const float*)d_in[2];
  const float* w2 = (const float*)d_in[3];
  const float* w3 = (const float*)d_in[4];
  const float* g1 = (const float*)d_in[5];
  const float* b1 = (const float*)d_in[6];
  const float* m1 = (const float*)d_in[7];
  const float* v1 = (const float*)d_in[8];
  const float* g2 = (const float*)d_in[9];
  const float* b2 = (const float*)d_in[10];
  const float* m2 = (const float*)d_in[11];
  const float* v2 = (const float*)d_in[12];
  const float* g3 = (const float*)d_in[13];
  const float* b3 = (const float*)d_in[14];
  const float* m3 = (const float*)d_in[15];
  const float* v3 = (const float*)d_in[16];

  char* ws = (char*)d_ws;
  unsigned char* hbuf = (unsigned char*)(ws + H_OFF);
  short* h2buf = (short*)(ws + H2_OFF);
  short* w1t   = (short*)(ws + W1T_OFF);
  short* w2s   = (short*)(ws + W2S_OFF);
  short* w3t   = (short*)(ws + W3T_OFF);
  float* bnc   = (float*)(ws + BNC_OFF);
  float* outp  = (float*)d_out;

  prep_kernel<<<128, 256, 0, stream>>>(w1, w2, w3,
                                       g1, b1, m1, v1,
                                       g2, b2, m2, v2,
                                       g3, b3, m3, v3,
                                       w1t, w2s, w3t, bnc);
  stage1_kernel<<<1563, 256, 0, stream>>>(x, w1t, bnc, hbuf);
  stage2_kernel<<<3125, 256, 0, stream>>>(hbuf, nb, w2s, bnc, h2buf);
  stage3_kernel<<<1563, 256, 0, stream>>>(h2buf, w3t, bnc, x, outp);
}

// Round 16
// 323.863 us; speedup vs baseline: 2.0480x; 1.0139x over previous
//
#include <hip/hip_runtime.h>

#define N_PTS 400000
#define EPS 1e-5f
#define H_DELTA (11.0f / 255.0f)
#define H_INV_DELTA (255.0f / 11.0f)

typedef __attribute__((ext_vector_type(8))) short short8;
typedef __attribute__((ext_vector_type(4))) float f32x4;
typedef __attribute__((ext_vector_type(2))) float f32x2;
typedef __attribute__((ext_vector_type(2))) unsigned long long ull2;

// ws layout (bytes)
constexpr size_t H_OFF   = 0;                        // h  uint8 [N][64] (k-permuted) = 25,600,000 B
constexpr size_t W1T_OFF = 102400000;                // w1t bf16 [64][128] = 16,384 B
constexpr size_t W2S_OFF = W1T_OFF + 16384;          // w2s bf16 [27][4096] (swizzled)
constexpr size_t W3T_OFF = W2S_OFF + 221184;         // w3t bf16 [128][64] = 16,384 B
constexpr size_t BNC_OFF = W3T_OFF + 16384;          // 512 f32

__device__ __forceinline__ short f2bf(float f) {
  unsigned u = __builtin_bit_cast(unsigned, f);
  u += 0x7FFFu + ((u >> 16) & 1u);   // RNE
  return (short)(u >> 16);
}

// HW packed f32->bf16 RNE (gfx950)
__device__ __forceinline__ unsigned cvtpk(float a, float b) {
  unsigned r;
  asm("v_cvt_pk_bf16_f32 %0, %1, %2" : "=v"(r) : "v"(a), "v"(b));
  return r;
}

// 8 uint8 -> 8 exact bf16 integers (ints 0..255 exact in bf16).
__device__ __forceinline__ short8 q2bf(unsigned long long v) {
  unsigned lo = (unsigned)v, hi = (unsigned)(v >> 32);
  union { unsigned u[4]; short8 s8; } r;
  r.u[0] = cvtpk((float)(lo & 0xff), (float)((lo >> 8) & 0xff));
  r.u[1] = cvtpk((float)((lo >> 16) & 0xff), (float)(lo >> 24));
  r.u[2] = cvtpk((float)(hi & 0xff), (float)((hi >> 8) & 0xff));
  r.u[3] = cvtpk((float)((hi >> 16) & 0xff), (float)(hi >> 24));
  return r.s8;
}

// ---------------- prep: weight transpose/convert + BN folding ----------------
__global__ __launch_bounds__(256) void prep_kernel(
    const float* __restrict__ w1, const float* __restrict__ w2,
    const float* __restrict__ w3,
    const float* __restrict__ g1, const float* __restrict__ b1,
    const float* __restrict__ m1, const float* __restrict__ v1,
    const float* __restrict__ g2, const float* __restrict__ b2,
    const float* __restrict__ m2, const float* __restrict__ v2,
    const float* __restrict__ g3, const float* __restrict__ b3,
    const float* __restrict__ m3, const float* __restrict__ v3,
    short* __restrict__ w1t, short* __restrict__ w2s,
    short* __restrict__ w3t, float* __restrict__ bnc) {
  int tid = blockIdx.x * 256 + threadIdx.x;
  int gs = gridDim.x * 256;
  for (int i = tid; i < 128 * 64; i += gs) {        // w1[k][n] -> w1t[n][k]
    int k = i >> 6, n = i & 63;
    w1t[n * 128 + k] = f2bf(w1[i]);
  }
  for (int i = tid; i < 27 * 64 * 64; i += gs) {    // w2[kk][k][n] -> swizzled w2s[kk][n][k]
    int kk = i >> 12, r = i & 4095, k = r >> 6, n = r & 63;
    int byte = (n * 64 + k) * 2;
    byte ^= (n & 7) << 4;                            // XOR swizzle (involution)
    w2s[kk * 4096 + (byte >> 1)] = f2bf(w2[i]);
  }
  for (int i = tid; i < 64 * 128; i += gs) {        // w3[k][n] -> w3t[n][k]
    int k = i >> 7, n = i & 127;
    w3t[n * 64 + k] = f2bf(w3[i]);
  }
  if (tid < 64) {
    float s = g1[tid] * rsqrtf(v1[tid] + EPS);
    bnc[tid] = s; bnc[64 + tid] = b1[tid] - m1[tid] * s;
  } else if (tid < 128) {
    int c = tid - 64;
    float s = g2[c] * rsqrtf(v2[c] + EPS);
    bnc[128 + c] = s; bnc[192 + c] = b2[c] - m2[c] * s;
  } else if (tid < 256) {
    int c = tid - 128;
    float s = g3[c] * rsqrtf(v3[c] + EPS);
    bnc[256 + c] = s; bnc[384 + c] = b3[c] - m3[c] * s;
  }
}

// ---------------- stage 1: h = quant_u8(relu(bn1(x @ w1))), k-permuted layout --
__global__ __launch_bounds__(256) void stage1_kernel(
    const float* __restrict__ x, const short* __restrict__ w1t,
    const float* __restrict__ bnc, unsigned char* __restrict__ h) {
  __shared__ __align__(16) unsigned char t1[4][16][80];   // u8, 16B-aligned rows
  const int lane = threadIdx.x & 63;
  const int wid = threadIdx.x >> 6;
  const int lr = lane & 15, lk = lane >> 4;
  const long wbase = ((long)blockIdx.x * 4 + wid) * 64;
  if (wbase >= N_PTS) return;

  short8 bf[4][4];
#pragma unroll
  for (int nf = 0; nf < 4; ++nf)
#pragma unroll
    for (int ks = 0; ks < 4; ++ks)
      bf[nf][ks] = *(const short8*)(w1t + (nf * 16 + lr) * 128 + ks * 32 + lk * 8);

  float s[4], t[4];
#pragma unroll
  for (int nf = 0; nf < 4; ++nf) {
    int ch = nf * 16 + lr;
    s[nf] = bnc[ch]; t[nf] = bnc[64 + ch];
  }

#pragma unroll
  for (int mt = 0; mt < 4; ++mt) {
    f32x4 acc[4];
#pragma unroll
    for (int nf = 0; nf < 4; ++nf) acc[nf] = f32x4{0.f, 0.f, 0.f, 0.f};
    const float* xr = x + (wbase + mt * 16 + lr) * 128 + lk * 8;
#pragma unroll
    for (int ks = 0; ks < 4; ++ks) {
      f32x4 lo = *(const f32x4*)(xr + ks * 32);
      f32x4 hi = *(const f32x4*)(xr + ks * 32 + 4);
      union { unsigned u[4]; short8 s8; } av;
      av.u[0] = cvtpk(lo[0], lo[1]);
      av.u[1] = cvtpk(lo[2], lo[3]);
      av.u[2] = cvtpk(hi[0], hi[1]);
      av.u[3] = cvtpk(hi[2], hi[3]);
#pragma unroll
      for (int nf = 0; nf < 4; ++nf)
        acc[nf] = __builtin_amdgcn_mfma_f32_16x16x32_bf16(av.s8, bf[nf][ks], acc[nf], 0, 0, 0);
    }
    // quantize -> per-wave LDS tile (k-permuted positions)
#pragma unroll
    for (int nf = 0; nf < 4; ++nf) {
      int pos = (((nf & 1) * 2 + (lr >> 3)) << 4) + ((nf >> 1) << 3) + (lr & 7);
#pragma unroll
      for (int j = 0; j < 4; ++j) {
        float v = acc[nf][j] * s[nf] + t[nf];
        v = v > 0.f ? v : 0.f;
        unsigned qi = (unsigned)(v * H_INV_DELTA + 0.5f);
        if (qi > 255u) qi = 255u;
        t1[wid][lk * 4 + j][pos] = (unsigned char)qi;
      }
    }
    asm volatile("s_waitcnt lgkmcnt(0)" ::: "memory");
    __builtin_amdgcn_sched_barrier(0);
    // coalesced store: lane -> (row = lane>>2, chunk = lane&3)
    {
      int row = lane >> 2, c = lane & 3;
      ull2 v = *(const ull2*)&t1[wid][row][c * 16];
      *(ull2*)(h + (wbase + mt * 16 + row) * 64 + c * 16) = v;
    }
    __builtin_amdgcn_sched_barrier(0);
  }
}

// ------- stage 2+3 fused: out = relu(bn3((relu(bn2(DELTA*sum_k q[nb[k]]@w2[k])))@w3) + x)
// k-loop identical to the proven 184us stage2. Epilogue: bn2->bf16 tileA
// (aliased on bbuf, safe after final barrier) -> stage3 MFMA (w3t L2-hot,
// lazy b3 loads) -> bn3 -> f32 tile3 -> coalesced residual+store.
// x/out streams overlap the gather-stall time; h2 round-trip eliminated.
__global__ __launch_bounds__(256, 4) void stage23_kernel(
    const unsigned char* __restrict__ h, const int* __restrict__ nb,
    const short* __restrict__ w2s, const short* __restrict__ w3t,
    const float* __restrict__ bnc, const float* __restrict__ x,
    float* __restrict__ out) {
  __shared__ __align__(16) short bbuf[2][4096];      // 16 KB double-buffered B; tileA alias later
  __shared__ float tile3[4][16][130];                // 33.3 KB f32 store-transpose tile
  const int tid = threadIdx.x;
  const int lane = tid & 63;
  const int wid = tid >> 6;
  const int lr = lane & 15, lk = lane >> 4;
  const long wbase = ((long)blockIdx.x * 4 + wid) * 32;
  const int chunk = tid ^ ((tid >> 3) & 3);          // bijective bank-spread permutation

  // swizzled LDS short-offsets for the 8 B-fragments
  int boff[4][2];
#pragma unroll
  for (int nf = 0; nf < 4; ++nf) {
    int row = nf * 16 + lr;
#pragma unroll
    for (int ks = 0; ks < 2; ++ks)
      boff[nf][ks] = ((row * 128 + ks * 64 + lk * 16) ^ ((row & 7) << 4)) >> 1;
  }

  f32x4 acc[2][4];
#pragma unroll
  for (int mt = 0; mt < 2; ++mt)
#pragma unroll
    for (int nf = 0; nf < 4; ++nf) acc[mt][nf] = f32x4{0.f, 0.f, 0.f, 0.f};

  const int* nb0 = nb + wbase + lr;            // + mt*16 + k*N_PTS

  int idxq[4][2];                               // ring, depth 4 (3 ahead)
  ull2 acur[2], anext[2];                       // 16B raw uint8 row chunk per mt

#pragma unroll
  for (int kk = 0; kk < 3; ++kk)
#pragma unroll
    for (int mt = 0; mt < 2; ++mt)
      idxq[kk][mt] = nb0[(long)kk * N_PTS + mt * 16];

#pragma unroll
  for (int mt = 0; mt < 2; ++mt)
    acur[mt] = *(const ull2*)(h + (long)idxq[0][mt] * 64 + lk * 16);

  {
    short8 b0a = *(const short8*)(w2s + chunk * 16);
    short8 b0b = *(const short8*)(w2s + chunk * 16 + 8);
    short8 b1a = *(const short8*)(w2s + 4096 + chunk * 16);
    short8 b1b = *(const short8*)(w2s + 4096 + chunk * 16 + 8);
    *(short8*)(&bbuf[0][chunk * 16]) = b0a;
    *(short8*)(&bbuf[0][chunk * 16 + 8]) = b0b;
    *(short8*)(&bbuf[1][chunk * 16]) = b1a;
    *(short8*)(&bbuf[1][chunk * 16 + 8]) = b1b;
  }
  asm volatile("s_waitcnt lgkmcnt(0)" ::: "memory");
  __builtin_amdgcn_s_barrier();

  // ---- main k-loop (identical to the 184us stage2) ----
#pragma unroll
  for (int k = 0; k < 27; ++k) {
    const int kp = k & 1;
    short8 bsa, bsb;
    if (k + 2 < 27) {
      bsa = *(const short8*)(w2s + (k + 2) * 4096 + chunk * 16);
      bsb = *(const short8*)(w2s + (k + 2) * 4096 + chunk * 16 + 8);
    }
    if (k + 3 < 27) {
#pragma unroll
      for (int mt = 0; mt < 2; ++mt)
        idxq[(k + 3) & 3][mt] = nb0[(long)(k + 3) * N_PTS + mt * 16];
    }
    if (k + 1 < 27) {
#pragma unroll
      for (int mt = 0; mt < 2; ++mt)
        anext[mt] = *(const ull2*)(h + (long)idxq[(k + 1) & 3][mt] * 64 + lk * 16);
    }
    short8 af[2][2];
#pragma unroll
    for (int mt = 0; mt < 2; ++mt) {
      af[mt][0] = q2bf(acur[mt][0]);
      af[mt][1] = q2bf(acur[mt][1]);
    }
#pragma unroll
    for (int nf = 0; nf < 4; ++nf) {
#pragma unroll
      for (int ks = 0; ks < 2; ++ks) {
        short8 bfr = *(const short8*)(&bbuf[kp][boff[nf][ks]]);
#pragma unroll
        for (int mt = 0; mt < 2; ++mt)
          acc[mt][nf] = __builtin_amdgcn_mfma_f32_16x16x32_bf16(af[mt][ks], bfr, acc[mt][nf], 0, 0, 0);
      }
    }
    asm volatile("s_waitcnt lgkmcnt(0)" ::: "memory");
    __builtin_amdgcn_s_barrier();
    if (k + 2 < 27) {
      *(short8*)(&bbuf[kp][chunk * 16]) = bsa;
      *(short8*)(&bbuf[kp][chunk * 16 + 8]) = bsb;
    }
    if (k + 1 < 27) {
#pragma unroll
      for (int mt = 0; mt < 2; ++mt)
        acur[mt] = anext[mt];
    }
  }
  // After the final barrier all waves are done with bbuf -> alias tileA on it.
  short* tileA = ((short*)bbuf) + wid * (16 * 72);   // per-wave [16][72] bf16

  float s2[4], t2[4];
#pragma unroll
  for (int nf = 0; nf < 4; ++nf) {
    int ch = nf * 16 + lr;
    s2[nf] = bnc[128 + ch] * H_DELTA; t2[nf] = bnc[192 + ch];
  }

#pragma unroll
  for (int mt = 0; mt < 2; ++mt) {
    // bn2 + relu -> bf16 A-tile
#pragma unroll
    for (int nf = 0; nf < 4; ++nf) {
      int ch = nf * 16 + lr;
#pragma unroll
      for (int j = 0; j < 4; ++j) {
        float v = acc[mt][nf][j] * s2[nf] + t2[nf];
        v = v > 0.f ? v : 0.f;
        tileA[(lk * 4 + j) * 72 + ch] = f2bf(v);
      }
    }
    asm volatile("s_waitcnt lgkmcnt(0)" ::: "memory");
    __builtin_amdgcn_sched_barrier(0);

    // stage 3 MFMA: A from tileA, B lazily from w3t (L2-hot 16KB)
    f32x4 acc3[8];
#pragma unroll
    for (int nf = 0; nf < 8; ++nf) acc3[nf] = f32x4{0.f, 0.f, 0.f, 0.f};
    short8 a3[2];
#pragma unroll
    for (int ks = 0; ks < 2; ++ks)
      a3[ks] = *(const short8*)&tileA[lr * 72 + ks * 32 + lk * 8];
#pragma unroll
    for (int nf = 0; nf < 8; ++nf) {
#pragma unroll
      for (int ks = 0; ks < 2; ++ks) {
        short8 b3 = *(const short8*)(w3t + (nf * 16 + lr) * 64 + ks * 32 + lk * 8);
        acc3[nf] = __builtin_amdgcn_mfma_f32_16x16x32_bf16(a3[ks], b3, acc3[nf], 0, 0, 0);
      }
    }
    __builtin_amdgcn_sched_barrier(0);

    // bn3 -> f32 tile (per-wave)
#pragma unroll
    for (int nf = 0; nf < 8; ++nf) {
      int ch = nf * 16 + lr;
      float s3 = bnc[256 + ch], t3 = bnc[384 + ch];
#pragma unroll
      for (int j = 0; j < 4; ++j)
        tile3[wid][lk * 4 + j][ch] = acc3[nf][j] * s3 + t3;
    }
    asm volatile("s_waitcnt lgkmcnt(0)" ::: "memory");
    __builtin_amdgcn_sched_barrier(0);

    // coalesced residual + relu + store (512B per row)
    const float* xr = x + (wbase + mt * 16) * 128 + 2 * lane;
    float* outr = out + (wbase + mt * 16) * 128 + 2 * lane;
#pragma unroll
    for (int r = 0; r < 16; ++r) {
      f32x2 tv = *(const f32x2*)&tile3[wid][r][2 * lane];
      f32x2 xv = *(const f32x2*)(xr + r * 128);
      float v0 = tv[0] + xv[0]; v0 = v0 > 0.f ? v0 : 0.f;
      float v1 = tv[1] + xv[1]; v1 = v1 > 0.f ? v1 : 0.f;
      *(f32x2*)(outr + r * 128) = f32x2{v0, v1};
    }
    __builtin_amdgcn_sched_barrier(0);
  }
}

extern "C" void kernel_launch(void* const* d_in, const int* in_sizes, int n_in,
                              void* d_out, int out_size, void* d_ws, size_t ws_size,
                              hipStream_t stream) {
  const float* x  = (const float*)d_in[0];
  const int*   nb = (const int*)d_in[1];
  const float* w1 = (const float*)d_in[2];
  const float* w2 = (const float*)d_in[3];
  const float* w3 = (const float*)d_in[4];
  const float* g1 = (const float*)d_in[5];
  const float* b1 = (const float*)d_in[6];
  const float* m1 = (const float*)d_in[7];
  const float* v1 = (const float*)d_in[8];
  const float* g2 = (const float*)d_in[9];
  const float* b2 = (const float*)d_in[10];
  const float* m2 = (const float*)d_in[11];
  const float* v2 = (const float*)d_in[12];
  const float* g3 = (const float*)d_in[13];
  const float* b3 = (const float*)d_in[14];
  const float* m3 = (const float*)d_in[15];
  const float* v3 = (const float*)d_in[16];

  char* ws = (char*)d_ws;
  unsigned char* hbuf = (unsigned char*)(ws + H_OFF);
  short* w1t   = (short*)(ws + W1T_OFF);
  short* w2s   = (short*)(ws + W2S_OFF);
  short* w3t   = (short*)(ws + W3T_OFF);
  float* bnc   = (float*)(ws + BNC_OFF);
  float* outp  = (float*)d_out;

  prep_kernel<<<128, 256, 0, stream>>>(w1, w2, w3,
                                       g1, b1, m1, v1,
                                       g2, b2, m2, v2,
                                       g3, b3, m3, v3,
                                       w1t, w2s, w3t, bnc);
  stage1_kernel<<<1563, 256, 0, stream>>>(x, w1t, bnc, hbuf);
  stage23_kernel<<<3125, 256, 0, stream>>>(hbuf, nb, w2s, w3t, bnc, x, outp);
}

// Round 17
// 315.088 us; speedup vs baseline: 2.1050x; 1.0278x over previous
//
#include <hip/hip_runtime.h>

#define N_PTS 400000
#define EPS 1e-5f
#define H_DELTA (11.0f / 255.0f)
#define H_INV_DELTA (255.0f / 11.0f)

typedef __attribute__((ext_vector_type(8))) short short8;
typedef __attribute__((ext_vector_type(4))) float f32x4;
typedef __attribute__((ext_vector_type(2))) float f32x2;
typedef __attribute__((ext_vector_type(2))) unsigned long long ull2;

// ws layout (bytes)
constexpr size_t H_OFF   = 0;                        // h  uint8 [N][64] (k-permuted) = 25,600,000 B
constexpr size_t W1T_OFF = 102400000;                // w1t bf16 [64][128] = 16,384 B
constexpr size_t W2S_OFF = W1T_OFF + 16384;          // w2s bf16 [27][4096] (swizzled)
constexpr size_t W3T_OFF = W2S_OFF + 221184;         // w3t bf16 [128][64] = 16,384 B
constexpr size_t BNC_OFF = W3T_OFF + 16384;          // 512 f32

__device__ __forceinline__ short f2bf(float f) {
  unsigned u = __builtin_bit_cast(unsigned, f);
  u += 0x7FFFu + ((u >> 16) & 1u);   // RNE
  return (short)(u >> 16);
}

// HW packed f32->bf16 RNE (gfx950)
__device__ __forceinline__ unsigned cvtpk(float a, float b) {
  unsigned r;
  asm("v_cvt_pk_bf16_f32 %0, %1, %2" : "=v"(r) : "v"(a), "v"(b));
  return r;
}

// 8 uint8 -> 8 exact bf16 integers (ints 0..255 exact in bf16).
__device__ __forceinline__ short8 q2bf(unsigned long long v) {
  unsigned lo = (unsigned)v, hi = (unsigned)(v >> 32);
  union { unsigned u[4]; short8 s8; } r;
  r.u[0] = cvtpk((float)(lo & 0xff), (float)((lo >> 8) & 0xff));
  r.u[1] = cvtpk((float)((lo >> 16) & 0xff), (float)(lo >> 24));
  r.u[2] = cvtpk((float)(hi & 0xff), (float)((hi >> 8) & 0xff));
  r.u[3] = cvtpk((float)((hi >> 16) & 0xff), (float)(hi >> 24));
  return r.s8;
}

// ---------------- prep: weight transpose/convert + BN folding ----------------
__global__ __launch_bounds__(256) void prep_kernel(
    const float* __restrict__ w1, const float* __restrict__ w2,
    const float* __restrict__ w3,
    const float* __restrict__ g1, const float* __restrict__ b1,
    const float* __restrict__ m1, const float* __restrict__ v1,
    const float* __restrict__ g2, const float* __restrict__ b2,
    const float* __restrict__ m2, const float* __restrict__ v2,
    const float* __restrict__ g3, const float* __restrict__ b3,
    const float* __restrict__ m3, const float* __restrict__ v3,
    short* __restrict__ w1t, short* __restrict__ w2s,
    short* __restrict__ w3t, float* __restrict__ bnc) {
  int tid = blockIdx.x * 256 + threadIdx.x;
  int gs = gridDim.x * 256;
  for (int i = tid; i < 128 * 64; i += gs) {        // w1[k][n] -> w1t[n][k]
    int k = i >> 6, n = i & 63;
    w1t[n * 128 + k] = f2bf(w1[i]);
  }
  for (int i = tid; i < 27 * 64 * 64; i += gs) {    // w2[kk][k][n] -> swizzled w2s[kk][n][k]
    int kk = i >> 12, r = i & 4095, k = r >> 6, n = r & 63;
    int byte = (n * 64 + k) * 2;
    byte ^= (n & 7) << 4;                            // XOR swizzle (involution)
    w2s[kk * 4096 + (byte >> 1)] = f2bf(w2[i]);
  }
  for (int i = tid; i < 64 * 128; i += gs) {        // w3[k][n] -> w3t[n][k]
    int k = i >> 7, n = i & 127;
    w3t[n * 64 + k] = f2bf(w3[i]);
  }
  if (tid < 64) {
    float s = g1[tid] * rsqrtf(v1[tid] + EPS);
    bnc[tid] = s; bnc[64 + tid] = b1[tid] - m1[tid] * s;
  } else if (tid < 128) {
    int c = tid - 64;
    float s = g2[c] * rsqrtf(v2[c] + EPS);
    bnc[128 + c] = s; bnc[192 + c] = b2[c] - m2[c] * s;
  } else if (tid < 256) {
    int c = tid - 128;
    float s = g3[c] * rsqrtf(v3[c] + EPS);
    bnc[256 + c] = s; bnc[384 + c] = b3[c] - m3[c] * s;
  }
}

// ---------------- stage 1: h = quant_u8(relu(bn1(x @ w1))), k-permuted layout --
__global__ __launch_bounds__(256) void stage1_kernel(
    const float* __restrict__ x, const short* __restrict__ w1t,
    const float* __restrict__ bnc, unsigned char* __restrict__ h) {
  __shared__ __align__(16) unsigned char t1[4][16][80];   // u8, 16B-aligned rows
  const int lane = threadIdx.x & 63;
  const int wid = threadIdx.x >> 6;
  const int lr = lane & 15, lk = lane >> 4;
  const long wbase = ((long)blockIdx.x * 4 + wid) * 64;
  if (wbase >= N_PTS) return;

  short8 bf[4][4];
#pragma unroll
  for (int nf = 0; nf < 4; ++nf)
#pragma unroll
    for (int ks = 0; ks < 4; ++ks)
      bf[nf][ks] = *(const short8*)(w1t + (nf * 16 + lr) * 128 + ks * 32 + lk * 8);

  float s[4], t[4];
#pragma unroll
  for (int nf = 0; nf < 4; ++nf) {
    int ch = nf * 16 + lr;
    s[nf] = bnc[ch]; t[nf] = bnc[64 + ch];
  }

#pragma unroll
  for (int mt = 0; mt < 4; ++mt) {
    f32x4 acc[4];
#pragma unroll
    for (int nf = 0; nf < 4; ++nf) acc[nf] = f32x4{0.f, 0.f, 0.f, 0.f};
    const float* xr = x + (wbase + mt * 16 + lr) * 128 + lk * 8;
#pragma unroll
    for (int ks = 0; ks < 4; ++ks) {
      f32x4 lo = *(const f32x4*)(xr + ks * 32);
      f32x4 hi = *(const f32x4*)(xr + ks * 32 + 4);
      union { unsigned u[4]; short8 s8; } av;
      av.u[0] = cvtpk(lo[0], lo[1]);
      av.u[1] = cvtpk(lo[2], lo[3]);
      av.u[2] = cvtpk(hi[0], hi[1]);
      av.u[3] = cvtpk(hi[2], hi[3]);
#pragma unroll
      for (int nf = 0; nf < 4; ++nf)
        acc[nf] = __builtin_amdgcn_mfma_f32_16x16x32_bf16(av.s8, bf[nf][ks], acc[nf], 0, 0, 0);
    }
    // quantize -> per-wave LDS tile (k-permuted positions)
#pragma unroll
    for (int nf = 0; nf < 4; ++nf) {
      int pos = (((nf & 1) * 2 + (lr >> 3)) << 4) + ((nf >> 1) << 3) + (lr & 7);
#pragma unroll
      for (int j = 0; j < 4; ++j) {
        float v = acc[nf][j] * s[nf] + t[nf];
        v = v > 0.f ? v : 0.f;
        unsigned qi = (unsigned)(v * H_INV_DELTA + 0.5f);
        if (qi > 255u) qi = 255u;
        t1[wid][lk * 4 + j][pos] = (unsigned char)qi;
      }
    }
    asm volatile("s_waitcnt lgkmcnt(0)" ::: "memory");
    __builtin_amdgcn_sched_barrier(0);
    // coalesced store: lane -> (row = lane>>2, chunk = lane&3)
    {
      int row = lane >> 2, c = lane & 3;
      ull2 v = *(const ull2*)&t1[wid][row][c * 16];
      *(ull2*)(h + (wbase + mt * 16 + row) * 64 + c * 16) = v;
    }
    __builtin_amdgcn_sched_barrier(0);
  }
}

// ------- stage 2+3 fused: out = relu(bn3((relu(bn2(DELTA*sum_k q[nb[k]]@w2[k])))@w3) + x)
// k-loop = proven 184us stage2. Epilogue: bn2->bf16 tileA (aliased on bbuf) ->
// stage3 MFMA -> bn3 -> two half-width f32 transpose passes (tile3 [16][66])
// -> coalesced 256B-row residual+store. LDS 33.3KB -> 4 blocks/CU (was 3).
__global__ __launch_bounds__(256, 4) void stage23_kernel(
    const unsigned char* __restrict__ h, const int* __restrict__ nb,
    const short* __restrict__ w2s, const short* __restrict__ w3t,
    const float* __restrict__ bnc, const float* __restrict__ x,
    float* __restrict__ out) {
  __shared__ __align__(16) short bbuf[2][4096];      // 16 KB double-buffered B; tileA alias later
  __shared__ float tile3[4][16][66];                 // 16.9 KB f32 half-width transpose tile
  const int tid = threadIdx.x;
  const int lane = tid & 63;
  const int wid = tid >> 6;
  const int lr = lane & 15, lk = lane >> 4;
  const long wbase = ((long)blockIdx.x * 4 + wid) * 32;
  const int chunk = tid ^ ((tid >> 3) & 3);          // bijective bank-spread permutation

  // swizzled LDS short-offsets for the 8 B-fragments
  int boff[4][2];
#pragma unroll
  for (int nf = 0; nf < 4; ++nf) {
    int row = nf * 16 + lr;
#pragma unroll
    for (int ks = 0; ks < 2; ++ks)
      boff[nf][ks] = ((row * 128 + ks * 64 + lk * 16) ^ ((row & 7) << 4)) >> 1;
  }

  f32x4 acc[2][4];
#pragma unroll
  for (int mt = 0; mt < 2; ++mt)
#pragma unroll
    for (int nf = 0; nf < 4; ++nf) acc[mt][nf] = f32x4{0.f, 0.f, 0.f, 0.f};

  const int* nb0 = nb + wbase + lr;            // + mt*16 + k*N_PTS

  int idxq[4][2];                               // ring, depth 4 (3 ahead)
  ull2 acur[2], anext[2];                       // 16B raw uint8 row chunk per mt

#pragma unroll
  for (int kk = 0; kk < 3; ++kk)
#pragma unroll
    for (int mt = 0; mt < 2; ++mt)
      idxq[kk][mt] = nb0[(long)kk * N_PTS + mt * 16];

#pragma unroll
  for (int mt = 0; mt < 2; ++mt)
    acur[mt] = *(const ull2*)(h + (long)idxq[0][mt] * 64 + lk * 16);

  {
    short8 b0a = *(const short8*)(w2s + chunk * 16);
    short8 b0b = *(const short8*)(w2s + chunk * 16 + 8);
    short8 b1a = *(const short8*)(w2s + 4096 + chunk * 16);
    short8 b1b = *(const short8*)(w2s + 4096 + chunk * 16 + 8);
    *(short8*)(&bbuf[0][chunk * 16]) = b0a;
    *(short8*)(&bbuf[0][chunk * 16 + 8]) = b0b;
    *(short8*)(&bbuf[1][chunk * 16]) = b1a;
    *(short8*)(&bbuf[1][chunk * 16 + 8]) = b1b;
  }
  asm volatile("s_waitcnt lgkmcnt(0)" ::: "memory");
  __builtin_amdgcn_s_barrier();

  // ---- main k-loop (identical to the 184us stage2) ----
#pragma unroll
  for (int k = 0; k < 27; ++k) {
    const int kp = k & 1;
    short8 bsa, bsb;
    if (k + 2 < 27) {
      bsa = *(const short8*)(w2s + (k + 2) * 4096 + chunk * 16);
      bsb = *(const short8*)(w2s + (k + 2) * 4096 + chunk * 16 + 8);
    }
    if (k + 3 < 27) {
#pragma unroll
      for (int mt = 0; mt < 2; ++mt)
        idxq[(k + 3) & 3][mt] = nb0[(long)(k + 3) * N_PTS + mt * 16];
    }
    if (k + 1 < 27) {
#pragma unroll
      for (int mt = 0; mt < 2; ++mt)
        anext[mt] = *(const ull2*)(h + (long)idxq[(k + 1) & 3][mt] * 64 + lk * 16);
    }
    short8 af[2][2];
#pragma unroll
    for (int mt = 0; mt < 2; ++mt) {
      af[mt][0] = q2bf(acur[mt][0]);
      af[mt][1] = q2bf(acur[mt][1]);
    }
#pragma unroll
    for (int nf = 0; nf < 4; ++nf) {
#pragma unroll
      for (int ks = 0; ks < 2; ++ks) {
        short8 bfr = *(const short8*)(&bbuf[kp][boff[nf][ks]]);
#pragma unroll
        for (int mt = 0; mt < 2; ++mt)
          acc[mt][nf] = __builtin_amdgcn_mfma_f32_16x16x32_bf16(af[mt][ks], bfr, acc[mt][nf], 0, 0, 0);
      }
    }
    asm volatile("s_waitcnt lgkmcnt(0)" ::: "memory");
    __builtin_amdgcn_s_barrier();
    if (k + 2 < 27) {
      *(short8*)(&bbuf[kp][chunk * 16]) = bsa;
      *(short8*)(&bbuf[kp][chunk * 16 + 8]) = bsb;
    }
    if (k + 1 < 27) {
#pragma unroll
      for (int mt = 0; mt < 2; ++mt)
        acur[mt] = anext[mt];
    }
  }
  // After the final barrier all waves are done with bbuf -> alias tileA on it.
  short* tileA = ((short*)bbuf) + wid * (16 * 72);   // per-wave [16][72] bf16

  float s2[4], t2[4];
#pragma unroll
  for (int nf = 0; nf < 4; ++nf) {
    int ch = nf * 16 + lr;
    s2[nf] = bnc[128 + ch] * H_DELTA; t2[nf] = bnc[192 + ch];
  }

#pragma unroll
  for (int mt = 0; mt < 2; ++mt) {
    // bn2 + relu -> bf16 A-tile
#pragma unroll
    for (int nf = 0; nf < 4; ++nf) {
      int ch = nf * 16 + lr;
#pragma unroll
      for (int j = 0; j < 4; ++j) {
        float v = acc[mt][nf][j] * s2[nf] + t2[nf];
        v = v > 0.f ? v : 0.f;
        tileA[(lk * 4 + j) * 72 + ch] = f2bf(v);
      }
    }
    asm volatile("s_waitcnt lgkmcnt(0)" ::: "memory");
    __builtin_amdgcn_sched_barrier(0);

    // stage 3 MFMA: A from tileA, B lazily from w3t (L2-hot 16KB)
    f32x4 acc3[8];
#pragma unroll
    for (int nf = 0; nf < 8; ++nf) acc3[nf] = f32x4{0.f, 0.f, 0.f, 0.f};
    short8 a3[2];
#pragma unroll
    for (int ks = 0; ks < 2; ++ks)
      a3[ks] = *(const short8*)&tileA[lr * 72 + ks * 32 + lk * 8];
#pragma unroll
    for (int nf = 0; nf < 8; ++nf) {
#pragma unroll
      for (int ks = 0; ks < 2; ++ks) {
        short8 b3 = *(const short8*)(w3t + (nf * 16 + lr) * 64 + ks * 32 + lk * 8);
        acc3[nf] = __builtin_amdgcn_mfma_f32_16x16x32_bf16(a3[ks], b3, acc3[nf], 0, 0, 0);
      }
    }
    __builtin_amdgcn_sched_barrier(0);

    // two half-width transpose passes: ch in [half*64, half*64+64)
#pragma unroll
    for (int half = 0; half < 2; ++half) {
#pragma unroll
      for (int nfh = 0; nfh < 4; ++nfh) {
        int nf = half * 4 + nfh;
        int ch = nf * 16 + lr;
        float s3 = bnc[256 + ch], t3 = bnc[384 + ch];
#pragma unroll
        for (int j = 0; j < 4; ++j)
          tile3[wid][lk * 4 + j][nfh * 16 + lr] = acc3[nf][j] * s3 + t3;
      }
      asm volatile("s_waitcnt lgkmcnt(0)" ::: "memory");
      __builtin_amdgcn_sched_barrier(0);

      const float* xr = x + (wbase + mt * 16) * 128 + half * 64 + lane;
      float* outr = out + (wbase + mt * 16) * 128 + half * 64 + lane;
#pragma unroll
      for (int r = 0; r < 16; ++r) {
        float v = tile3[wid][r][lane] + xr[r * 128];
        outr[r * 128] = v > 0.f ? v : 0.f;
      }
      __builtin_amdgcn_sched_barrier(0);
    }
  }
}

extern "C" void kernel_launch(void* const* d_in, const int* in_sizes, int n_in,
                              void* d_out, int out_size, void* d_ws, size_t ws_size,
                              hipStream_t stream) {
  const float* x  = (const float*)d_in[0];
  const int*   nb = (const int*)d_in[1];
  const float* w1 = (const float*)d_in[2];
  const float* w2 = (const float*)d_in[3];
  const float* w3 = (const float*)d_in[4];
  const float* g1 = (const float*)d_in[5];
  const float* b1 = (const float*)d_in[6];
  const float* m1 = (const float*)d_in[7];
  const float* v1 = (const float*)d_in[8];
  const float* g2 = (const float*)d_in[9];
  const float* b2 = (const float*)d_in[10];
  const float* m2 = (const float*)d_in[11];
  const float* v2 = (const float*)d_in[12];
  const float* g3 = (const float*)d_in[13];
  const float* b3 = (const float*)d_in[14];
  const float* m3 = (const float*)d_in[15];
  const float* v3 = (const float*)d_in[16];

  char* ws = (char*)d_ws;
  unsigned char* hbuf = (unsigned char*)(ws + H_OFF);
  short* w1t   = (short*)(ws + W1T_OFF);
  short* w2s   = (short*)(ws + W2S_OFF);
  short* w3t   = (short*)(ws + W3T_OFF);
  float* bnc   = (float*)(ws + BNC_OFF);
  float* outp  = (float*)d_out;

  prep_kernel<<<128, 256, 0, stream>>>(w1, w2, w3,
                                       g1, b1, m1, v1,
                                       g2, b2, m2, v2,
                                       g3, b3, m3, v3,
                                       w1t, w2s, w3t, bnc);
  stage1_kernel<<<1563, 256, 0, stream>>>(x, w1t, bnc, hbuf);
  stage23_kernel<<<3125, 256, 0, stream>>>(hbuf, nb, w2s, w3t, bnc, x, outp);
}